// Round 2
// baseline (3596.708 us; speedup 1.0000x reference)
//
#include <hip/hip_runtime.h>
#include <hip/hip_bf16.h>

#define T_DIM 4096
#define D_DIM 1024
#define DFF   2048
#define E_NUM 8

typedef short short8 __attribute__((ext_vector_type(8)));
typedef float f32x4  __attribute__((ext_vector_type(4)));

__device__ __forceinline__ unsigned short f2bf(float f) {
  union { float f; unsigned u; } v; v.f = f;
  unsigned r = v.u + 0x7FFFu + ((v.u >> 16) & 1u);   // round-to-nearest-even
  return (unsigned short)(r >> 16);
}

__device__ __forceinline__ void load_lds16(const unsigned short* g, unsigned short* l) {
  __builtin_amdgcn_global_load_lds((const __attribute__((address_space(1))) void*)g,
                                   (__attribute__((address_space(3))) void*)l, 16, 0, 0);
}

// ---------------- probe: logits/scale in full fp32 (mask boundary is precision-sensitive)
__global__ void probe_kernel(const float* __restrict__ x, const float* __restrict__ Wp,
                             const float* __restrict__ bp, const float* __restrict__ tb,
                             const float* __restrict__ gm, const float* __restrict__ wdp,
                             float* __restrict__ scale) {
  int wave = threadIdx.x >> 6;
  int lane = threadIdx.x & 63;
  int task = blockIdx.x * 4 + wave;          // one wave per (token, expert)
  int t = task >> 3, e = task & 7;
  const float4* xr = (const float4*)(x + (size_t)t * D_DIM);
  const float4* wr = (const float4*)(Wp + (size_t)e * D_DIM);
  float acc = 0.f;
#pragma unroll
  for (int k = 0; k < 4; k++) {
    float4 a = xr[k * 64 + lane];
    float4 b = wr[k * 64 + lane];
    acc += a.x * b.x + a.y * b.y + a.z * b.z + a.w * b.w;
  }
#pragma unroll
  for (int off = 32; off > 0; off >>= 1) acc += __shfl_down(acc, off);
  if (lane == 0) {
    float logit = acc + bp[e];
    float z = wdp[0] * 0.5f;                                  // w_depth * depth_ratio
    float tau = tb[0] + gm[0] * (z / (1.f + expf(-z)));       // tau_base + gamma*silu(z)
    float s = (logit > tau) ? (1.f / (1.f + expf(-logit))) : 0.f;
    scale[t * E_NUM + e] = s;
  }
}

// ---------------- fp32 -> bf16 converters
__global__ void cvt_kernel(const float* __restrict__ src, unsigned short* __restrict__ dst) {
  int i = blockIdx.x * 256 + threadIdx.x;   // one float4 per thread
  float4 v = ((const float4*)src)[i];
  ushort4 o;
  o.x = f2bf(v.x); o.y = f2bf(v.y); o.z = f2bf(v.z); o.w = f2bf(v.w);
  ((ushort4*)dst)[i] = o;
}

__global__ void cvt3_kernel(const float* __restrict__ wu, const float* __restrict__ wg,
                            const float* __restrict__ wdn,
                            unsigned short* __restrict__ ou, unsigned short* __restrict__ og,
                            unsigned short* __restrict__ od) {
  int b = blockIdx.x;                 // 3 * 2048 blocks; 2048 per matrix
  int m = b >> 11;
  int i = (b & 2047) * 256 + threadIdx.x;
  const float* s = (m == 0) ? wu : (m == 1) ? wg : wdn;
  unsigned short* d = (m == 0) ? ou : (m == 1) ? og : od;
  float4 v = ((const float4*)s)[i];
  ushort4 o;
  o.x = f2bf(v.x); o.y = f2bf(v.y); o.z = f2bf(v.z); o.w = f2bf(v.w);
  ((ushort4*)d)[i] = o;
}

// ---------------- up+gate GEMM (C = A·Bt for both Bu,Bg), fused silu·scale -> bf16 h'
// A: x_bf16 [T][D], Bu/Bg: [DFF][D] (N-major = Bt form), H: [T][DFF]
// Epilogue stages the 128x128 bf16 tile in LDS, then writes with 16B/lane stores
// (the R1 2-byte scattered stores caused ~1.1 GB/dispatch of RMW write traffic).
#define SH_STRIDE 136   // shorts; 272 B row pitch: 16B-aligned, quads split banks
__global__ void upgate_kernel(const unsigned short* __restrict__ A,
                              const unsigned short* __restrict__ Bu,
                              const unsigned short* __restrict__ Bg,
                              const float* __restrict__ scale, int e,
                              unsigned short* __restrict__ H) {
  __shared__ unsigned short smem[3 * 128 * 32];          // 24576 B staging
  __shared__ unsigned short sH[128 * SH_STRIDE];         // 34816 B epilogue tile
  unsigned short* sA = smem;
  unsigned short* sU = smem + 4096;
  unsigned short* sG = smem + 8192;
  const int tid = threadIdx.x;
  const int wave = tid >> 6, lane = tid & 63;
  const int quad = lane >> 4, l15 = lane & 15;
  const int wm = (wave >> 1) * 64, wn = (wave & 1) * 64;
  const int rowA0 = blockIdx.x * 128;
  const int rowB0 = blockIdx.y * 128;

  f32x4 accU[4][4], accG[4][4];
#pragma unroll
  for (int i = 0; i < 4; i++)
#pragma unroll
    for (int j = 0; j < 4; j++) {
      accU[i][j] = (f32x4){0.f, 0.f, 0.f, 0.f};
      accG[i][j] = (f32x4){0.f, 0.f, 0.f, 0.f};
    }

  const int j0 = tid, j1 = tid + 256;          // 512 x 16B chunks per 8KB tile
  const int ar0 = rowA0 + (j0 >> 2), ar1 = rowA0 + (j1 >> 2);
  const int br0 = rowB0 + (j0 >> 2), br1 = rowB0 + (j1 >> 2);
  const int c0 = (j0 & 3) * 8, c1 = (j1 & 3) * 8;

  for (int k0 = 0; k0 < D_DIM; k0 += 32) {
    __syncthreads();
    load_lds16(A  + (size_t)ar0 * D_DIM + k0 + c0, sA + j0 * 8);
    load_lds16(A  + (size_t)ar1 * D_DIM + k0 + c1, sA + j1 * 8);
    load_lds16(Bu + (size_t)br0 * D_DIM + k0 + c0, sU + j0 * 8);
    load_lds16(Bu + (size_t)br1 * D_DIM + k0 + c1, sU + j1 * 8);
    load_lds16(Bg + (size_t)br0 * D_DIM + k0 + c0, sG + j0 * 8);
    load_lds16(Bg + (size_t)br1 * D_DIM + k0 + c1, sG + j1 * 8);
    __syncthreads();

    short8 af[4], bu[4], bg[4];
#pragma unroll
    for (int mt = 0; mt < 4; mt++)
      af[mt] = *(const short8*)(sA + (wm + mt * 16 + l15) * 32 + quad * 8);
#pragma unroll
    for (int nt = 0; nt < 4; nt++) {
      bu[nt] = *(const short8*)(sU + (wn + nt * 16 + l15) * 32 + quad * 8);
      bg[nt] = *(const short8*)(sG + (wn + nt * 16 + l15) * 32 + quad * 8);
    }
#pragma unroll
    for (int mt = 0; mt < 4; mt++)
#pragma unroll
      for (int nt = 0; nt < 4; nt++) {
        accU[mt][nt] = __builtin_amdgcn_mfma_f32_16x16x32_bf16(af[mt], bu[nt], accU[mt][nt], 0, 0, 0);
        accG[mt][nt] = __builtin_amdgcn_mfma_f32_16x16x32_bf16(af[mt], bg[nt], accG[mt][nt], 0, 0, 0);
      }
  }

  // epilogue: h' = scale[t,e] * up * silu(gate); stage tile in LDS, then
  // coalesced 16B/lane global stores.  C/D layout: col=lane&15, row=quad*4+reg
#pragma unroll
  for (int mt = 0; mt < 4; mt++) {
#pragma unroll
    for (int r = 0; r < 4; r++) {
      int lrow = wm + mt * 16 + quad * 4 + r;
      float s = scale[(rowA0 + lrow) * E_NUM + e];
#pragma unroll
      for (int nt = 0; nt < 4; nt++) {
        int lcol = wn + nt * 16 + l15;
        float u = accU[mt][nt][r];
        float g = accG[mt][nt][r];
        float h = s * u * (g / (1.f + __expf(-g)));
        sH[lrow * SH_STRIDE + lcol] = f2bf(h);
      }
    }
  }
  __syncthreads();
  // 128x128 shorts = 2048 chunks of 8 shorts (16B); 8 chunks per thread
#pragma unroll
  for (int c = 0; c < 8; c++) {
    int idx = c * 256 + tid;
    int row = idx >> 4;            // 16 chunks per row
    int col = (idx & 15) * 8;
    *(short8*)(H + (size_t)(rowA0 + row) * DFF + rowB0 + col) =
        *(const short8*)(sH + row * SH_STRIDE + col);
  }
}

// ---------------- down GEMM-accumulate: out[t,d] (+)= h' @ Wd^T
// A: h' [T][DFF], B: wd_bf16 [D][DFF] (N-major), out fp32 [T][D]
// Epilogue staged per-mt (32 rows x 128 cols fp32) in LDS; float4 read-add-write.
#define SF_STRIDE 132   // floats; 528 B pitch: 16B-aligned, conflict-free
__global__ void down_kernel(const unsigned short* __restrict__ A,
                            const unsigned short* __restrict__ B,
                            float* __restrict__ out, int accumulate) {
  __shared__ unsigned short smem[2 * 128 * 32];   // 16384 B staging
  __shared__ float sF[32 * SF_STRIDE];            // 16896 B epilogue tile
  unsigned short* sA = smem;
  unsigned short* sB = smem + 4096;
  const int tid = threadIdx.x;
  const int wave = tid >> 6, lane = tid & 63;
  const int quad = lane >> 4, l15 = lane & 15;
  const int gr = wave >> 1;                       // row group (0/1)
  const int wm = gr * 64, wn = (wave & 1) * 64;
  const int rowA0 = blockIdx.x * 128;
  const int rowB0 = blockIdx.y * 128;

  f32x4 acc[4][4];
#pragma unroll
  for (int i = 0; i < 4; i++)
#pragma unroll
    for (int j = 0; j < 4; j++) acc[i][j] = (f32x4){0.f, 0.f, 0.f, 0.f};

  const int j0 = tid, j1 = tid + 256;
  const int ar0 = rowA0 + (j0 >> 2), ar1 = rowA0 + (j1 >> 2);
  const int br0 = rowB0 + (j0 >> 2), br1 = rowB0 + (j1 >> 2);
  const int c0 = (j0 & 3) * 8, c1 = (j1 & 3) * 8;

  for (int k0 = 0; k0 < DFF; k0 += 32) {
    __syncthreads();
    load_lds16(A + (size_t)ar0 * DFF + k0 + c0, sA + j0 * 8);
    load_lds16(A + (size_t)ar1 * DFF + k0 + c1, sA + j1 * 8);
    load_lds16(B + (size_t)br0 * DFF + k0 + c0, sB + j0 * 8);
    load_lds16(B + (size_t)br1 * DFF + k0 + c1, sB + j1 * 8);
    __syncthreads();

    short8 af[4], bf[4];
#pragma unroll
    for (int mt = 0; mt < 4; mt++)
      af[mt] = *(const short8*)(sA + (wm + mt * 16 + l15) * 32 + quad * 8);
#pragma unroll
    for (int nt = 0; nt < 4; nt++)
      bf[nt] = *(const short8*)(sB + (wn + nt * 16 + l15) * 32 + quad * 8);
#pragma unroll
    for (int mt = 0; mt < 4; mt++)
#pragma unroll
      for (int nt = 0; nt < 4; nt++)
        acc[mt][nt] = __builtin_amdgcn_mfma_f32_16x16x32_bf16(af[mt], bf[nt], acc[mt][nt], 0, 0, 0);
  }

  // staged epilogue: per mt, rows {gr*64 + mt*16 + 0..15}, all 128 cols
#pragma unroll
  for (int mt = 0; mt < 4; mt++) {
    __syncthreads();   // protect sF from previous iteration's readers
#pragma unroll
    for (int r = 0; r < 4; r++) {
      int srow = gr * 16 + quad * 4 + r;          // 0..31
#pragma unroll
      for (int nt = 0; nt < 4; nt++) {
        int col = wn + nt * 16 + l15;
        sF[srow * SF_STRIDE + col] = acc[mt][nt][r];
      }
    }
    __syncthreads();
    // 32 rows x 128 cols fp32 = 1024 float4 chunks; 4 per thread
#pragma unroll
    for (int c = 0; c < 4; c++) {
      int idx = c * 256 + tid;
      int srow = idx >> 5;           // 32 chunks per row
      int col = (idx & 31) * 4;
      int grow = rowA0 + (srow >> 4) * 64 + mt * 16 + (srow & 15);
      float4 v = *(const float4*)(sF + srow * SF_STRIDE + col);
      float* gp = out + (size_t)grow * D_DIM + rowB0 + col;
      if (accumulate) {
        float4 o = *(const float4*)gp;
        v.x += o.x; v.y += o.y; v.z += o.z; v.w += o.w;
      }
      *(float4*)gp = v;
    }
  }
}

extern "C" void kernel_launch(void* const* d_in, const int* in_sizes, int n_in,
                              void* d_out, int out_size, void* d_ws, size_t ws_size,
                              hipStream_t stream) {
  const float* x   = (const float*)d_in[0];
  const float* Wp  = (const float*)d_in[1];
  const float* bp  = (const float*)d_in[2];
  const float* Wu  = (const float*)d_in[3];
  const float* Wg  = (const float*)d_in[4];
  const float* Wd  = (const float*)d_in[5];
  const float* tb  = (const float*)d_in[6];
  const float* gm  = (const float*)d_in[7];
  const float* wdp = (const float*)d_in[8];
  float* out = (float*)d_out;

  // workspace layout (total ~38 MB)
  char* ws = (char*)d_ws;
  float* scale          = (float*)ws;                                  // 131072 B
  unsigned short* xb    = (unsigned short*)(ws + 131072);              // 8 MB
  unsigned short* wub   = (unsigned short*)(ws + 131072 + 8388608);    // 4 MB
  unsigned short* wgb   = wub + (size_t)DFF * D_DIM;                   // 4 MB
  unsigned short* wdb   = wgb + (size_t)DFF * D_DIM;                   // 4 MB
  unsigned short* hbuf  = wdb + (size_t)DFF * D_DIM;                   // 16 MB

  probe_kernel<<<T_DIM * E_NUM / 4, 256, 0, stream>>>(x, Wp, bp, tb, gm, wdp, scale);
  cvt_kernel<<<T_DIM * D_DIM / 1024, 256, 0, stream>>>(x, xb);

  for (int e = 0; e < E_NUM; e++) {
    const size_t wsz = (size_t)DFF * D_DIM;
    cvt3_kernel<<<3 * (DFF * D_DIM / 1024), 256, 0, stream>>>(
        Wu + e * wsz, Wg + e * wsz, Wd + e * wsz, wub, wgb, wdb);
    dim3 g1(T_DIM / 128, DFF / 128);
    upgate_kernel<<<g1, 256, 0, stream>>>(xb, wub, wgb, scale, e, hbuf);
    dim3 g2(T_DIM / 128, D_DIM / 128);
    down_kernel<<<g2, 256, 0, stream>>>(hbuf, wdb, out, e > 0);
  }
}

// Round 3
// 1233.389 us; speedup vs baseline: 2.9161x; 2.9161x over previous
//
#include <hip/hip_runtime.h>
#include <hip/hip_bf16.h>

#define T_DIM 4096
#define D_DIM 1024
#define DFF   2048
#define E_NUM 8

typedef short short8 __attribute__((ext_vector_type(8)));
typedef float f32x4  __attribute__((ext_vector_type(4)));

__device__ __forceinline__ unsigned short f2bf(float f) {
  union { float f; unsigned u; } v; v.f = f;
  unsigned r = v.u + 0x7FFFu + ((v.u >> 16) & 1u);   // round-to-nearest-even
  return (unsigned short)(r >> 16);
}

__device__ __forceinline__ void load_lds16(const unsigned short* g, unsigned short* l) {
  __builtin_amdgcn_global_load_lds((const __attribute__((address_space(1))) void*)g,
                                   (__attribute__((address_space(3))) void*)l, 16, 0, 0);
}

// ---------------- probe: logits/scale in full fp32 (mask boundary is precision-sensitive)
__global__ void probe_kernel(const float* __restrict__ x, const float* __restrict__ Wp,
                             const float* __restrict__ bp, const float* __restrict__ tb,
                             const float* __restrict__ gm, const float* __restrict__ wdp,
                             float* __restrict__ scale) {
  int wave = threadIdx.x >> 6;
  int lane = threadIdx.x & 63;
  int task = blockIdx.x * 4 + wave;          // one wave per (token, expert)
  int t = task >> 3, e = task & 7;
  const float4* xr = (const float4*)(x + (size_t)t * D_DIM);
  const float4* wr = (const float4*)(Wp + (size_t)e * D_DIM);
  float acc = 0.f;
#pragma unroll
  for (int k = 0; k < 4; k++) {
    float4 a = xr[k * 64 + lane];
    float4 b = wr[k * 64 + lane];
    acc += a.x * b.x + a.y * b.y + a.z * b.z + a.w * b.w;
  }
#pragma unroll
  for (int off = 32; off > 0; off >>= 1) acc += __shfl_down(acc, off);
  if (lane == 0) {
    float logit = acc + bp[e];
    float z = wdp[0] * 0.5f;                                  // w_depth * depth_ratio
    float tau = tb[0] + gm[0] * (z / (1.f + expf(-z)));       // tau_base + gamma*silu(z)
    float s = (logit > tau) ? (1.f / (1.f + expf(-logit))) : 0.f;
    scale[t * E_NUM + e] = s;
  }
}

// ---------------- fp32 -> bf16 converters
__global__ void cvt_kernel(const float* __restrict__ src, unsigned short* __restrict__ dst) {
  int i = blockIdx.x * 256 + threadIdx.x;   // one float4 per thread
  float4 v = ((const float4*)src)[i];
  ushort4 o;
  o.x = f2bf(v.x); o.y = f2bf(v.y); o.z = f2bf(v.z); o.w = f2bf(v.w);
  ((ushort4*)dst)[i] = o;
}

__global__ void cvt3_kernel(const float* __restrict__ wu, const float* __restrict__ wg,
                            const float* __restrict__ wdn,
                            unsigned short* __restrict__ ou, unsigned short* __restrict__ og,
                            unsigned short* __restrict__ od) {
  int b = blockIdx.x;                 // 3 * 2048 blocks; 2048 per matrix
  int m = b >> 11;
  int i = (b & 2047) * 256 + threadIdx.x;
  const float* s = (m == 0) ? wu : (m == 1) ? wg : wdn;
  unsigned short* d = (m == 0) ? ou : (m == 1) ? og : od;
  float4 v = ((const float4*)s)[i];
  ushort4 o;
  o.x = f2bf(v.x); o.y = f2bf(v.y); o.z = f2bf(v.z); o.w = f2bf(v.w);
  ((ushort4*)d)[i] = o;
}

// ---------------- up+gate GEMM (C = A·Bt for both Bu,Bg), fused silu·scale -> bf16 h'
// A: x_bf16 [T][D], Bu/Bg: [DFF][D] (N-major = Bt form), H: [T][DFF]
// __launch_bounds__(256,1): R1/R2 showed VGPR_Count=64 with ~180 regs of live
// state -> compiler spilled accumulators to scratch (~2 GB/dispatch RMW traffic,
// the real cause of the 1.2 GB WRITE_SIZE). Cap occupancy pressure, no spill.
__global__ void __launch_bounds__(256, 1)
upgate_kernel(const unsigned short* __restrict__ A,
              const unsigned short* __restrict__ Bu,
              const unsigned short* __restrict__ Bg,
              const float* __restrict__ scale, int e,
              unsigned short* __restrict__ H) {
  __shared__ unsigned short smem[3 * 128 * 32];          // 24576 B staging
  unsigned short* sA = smem;
  unsigned short* sU = smem + 4096;
  unsigned short* sG = smem + 8192;
  const int tid = threadIdx.x;
  const int wave = tid >> 6, lane = tid & 63;
  const int quad = lane >> 4, l15 = lane & 15;
  const int wm = (wave >> 1) * 64, wn = (wave & 1) * 64;
  const int rowA0 = blockIdx.x * 128;
  const int rowB0 = blockIdx.y * 128;

  f32x4 accU[4][4], accG[4][4];
#pragma unroll
  for (int i = 0; i < 4; i++)
#pragma unroll
    for (int j = 0; j < 4; j++) {
      accU[i][j] = (f32x4){0.f, 0.f, 0.f, 0.f};
      accG[i][j] = (f32x4){0.f, 0.f, 0.f, 0.f};
    }

  const int j0 = tid, j1 = tid + 256;          // 512 x 16B chunks per 8KB tile
  const int ar0 = rowA0 + (j0 >> 2), ar1 = rowA0 + (j1 >> 2);
  const int br0 = rowB0 + (j0 >> 2), br1 = rowB0 + (j1 >> 2);
  const int c0 = (j0 & 3) * 8, c1 = (j1 & 3) * 8;

  for (int k0 = 0; k0 < D_DIM; k0 += 32) {
    __syncthreads();
    load_lds16(A  + (size_t)ar0 * D_DIM + k0 + c0, sA + j0 * 8);
    load_lds16(A  + (size_t)ar1 * D_DIM + k0 + c1, sA + j1 * 8);
    load_lds16(Bu + (size_t)br0 * D_DIM + k0 + c0, sU + j0 * 8);
    load_lds16(Bu + (size_t)br1 * D_DIM + k0 + c1, sU + j1 * 8);
    load_lds16(Bg + (size_t)br0 * D_DIM + k0 + c0, sG + j0 * 8);
    load_lds16(Bg + (size_t)br1 * D_DIM + k0 + c1, sG + j1 * 8);
    __syncthreads();

    short8 af[4], bu[4], bg[4];
#pragma unroll
    for (int mt = 0; mt < 4; mt++)
      af[mt] = *(const short8*)(sA + (wm + mt * 16 + l15) * 32 + quad * 8);
#pragma unroll
    for (int nt = 0; nt < 4; nt++) {
      bu[nt] = *(const short8*)(sU + (wn + nt * 16 + l15) * 32 + quad * 8);
      bg[nt] = *(const short8*)(sG + (wn + nt * 16 + l15) * 32 + quad * 8);
    }
#pragma unroll
    for (int mt = 0; mt < 4; mt++)
#pragma unroll
      for (int nt = 0; nt < 4; nt++) {
        accU[mt][nt] = __builtin_amdgcn_mfma_f32_16x16x32_bf16(af[mt], bu[nt], accU[mt][nt], 0, 0, 0);
        accG[mt][nt] = __builtin_amdgcn_mfma_f32_16x16x32_bf16(af[mt], bg[nt], accG[mt][nt], 0, 0, 0);
      }
  }

  // epilogue: h' = scale[t,e] * up * silu(gate)  (C/D: col=lane&15, row=quad*4+reg)
  // Direct 2B stores: R2 proved these are NOT a traffic problem (L2 merges the
  // block's full tile coverage); keeping LDS at 24KB preserves occupancy.
#pragma unroll
  for (int mt = 0; mt < 4; mt++) {
#pragma unroll
    for (int r = 0; r < 4; r++) {
      int row = rowA0 + wm + mt * 16 + quad * 4 + r;
      float s = scale[row * E_NUM + e];
#pragma unroll
      for (int nt = 0; nt < 4; nt++) {
        int col = rowB0 + wn + nt * 16 + l15;
        float u = accU[mt][nt][r];
        float g = accG[mt][nt][r];
        float h = s * u * (g / (1.f + __expf(-g)));
        H[(size_t)row * DFF + col] = f2bf(h);
      }
    }
  }
}

// ---------------- down GEMM-accumulate: out[t,d] (+)= h' @ Wd^T
// A: h' [T][DFF], B: wd_bf16 [D][DFF] (N-major), out fp32 [T][D]
#define SF_STRIDE 132   // floats; 528 B pitch: 16B-aligned, conflict-free
__global__ void __launch_bounds__(256, 1)
down_kernel(const unsigned short* __restrict__ A,
            const unsigned short* __restrict__ B,
            float* __restrict__ out, int accumulate) {
  __shared__ unsigned short smem[2 * 128 * 32];   // 16384 B staging
  __shared__ float sF[32 * SF_STRIDE];            // 16896 B epilogue tile
  unsigned short* sA = smem;
  unsigned short* sB = smem + 4096;
  const int tid = threadIdx.x;
  const int wave = tid >> 6, lane = tid & 63;
  const int quad = lane >> 4, l15 = lane & 15;
  const int gr = wave >> 1;                       // row group (0/1)
  const int wm = gr * 64, wn = (wave & 1) * 64;
  const int rowA0 = blockIdx.x * 128;
  const int rowB0 = blockIdx.y * 128;

  f32x4 acc[4][4];
#pragma unroll
  for (int i = 0; i < 4; i++)
#pragma unroll
    for (int j = 0; j < 4; j++) acc[i][j] = (f32x4){0.f, 0.f, 0.f, 0.f};

  const int j0 = tid, j1 = tid + 256;
  const int ar0 = rowA0 + (j0 >> 2), ar1 = rowA0 + (j1 >> 2);
  const int br0 = rowB0 + (j0 >> 2), br1 = rowB0 + (j1 >> 2);
  const int c0 = (j0 & 3) * 8, c1 = (j1 & 3) * 8;

  for (int k0 = 0; k0 < DFF; k0 += 32) {
    __syncthreads();
    load_lds16(A + (size_t)ar0 * DFF + k0 + c0, sA + j0 * 8);
    load_lds16(A + (size_t)ar1 * DFF + k0 + c1, sA + j1 * 8);
    load_lds16(B + (size_t)br0 * DFF + k0 + c0, sB + j0 * 8);
    load_lds16(B + (size_t)br1 * DFF + k0 + c1, sB + j1 * 8);
    __syncthreads();

    short8 af[4], bf[4];
#pragma unroll
    for (int mt = 0; mt < 4; mt++)
      af[mt] = *(const short8*)(sA + (wm + mt * 16 + l15) * 32 + quad * 8);
#pragma unroll
    for (int nt = 0; nt < 4; nt++)
      bf[nt] = *(const short8*)(sB + (wn + nt * 16 + l15) * 32 + quad * 8);
#pragma unroll
    for (int mt = 0; mt < 4; mt++)
#pragma unroll
      for (int nt = 0; nt < 4; nt++)
        acc[mt][nt] = __builtin_amdgcn_mfma_f32_16x16x32_bf16(af[mt], bf[nt], acc[mt][nt], 0, 0, 0);
  }

  // staged epilogue: per mt, rows {gr*64 + mt*16 + 0..15}, all 128 cols
#pragma unroll
  for (int mt = 0; mt < 4; mt++) {
    __syncthreads();   // protect sF from previous iteration's readers
#pragma unroll
    for (int r = 0; r < 4; r++) {
      int srow = gr * 16 + quad * 4 + r;          // 0..31
#pragma unroll
      for (int nt = 0; nt < 4; nt++) {
        int col = wn + nt * 16 + l15;
        sF[srow * SF_STRIDE + col] = acc[mt][nt][r];
      }
    }
    __syncthreads();
    // 32 rows x 128 cols fp32 = 1024 float4 chunks; 4 per thread
#pragma unroll
    for (int c = 0; c < 4; c++) {
      int idx = c * 256 + tid;
      int srow = idx >> 5;           // 32 chunks per row
      int col = (idx & 31) * 4;
      int grow = rowA0 + (srow >> 4) * 64 + mt * 16 + (srow & 15);
      float4 v = *(const float4*)(sF + srow * SF_STRIDE + col);
      float* gp = out + (size_t)grow * D_DIM + rowB0 + col;
      if (accumulate) {
        float4 o = *(const float4*)gp;
        v.x += o.x; v.y += o.y; v.z += o.z; v.w += o.w;
      }
      *(float4*)gp = v;
    }
  }
}

extern "C" void kernel_launch(void* const* d_in, const int* in_sizes, int n_in,
                              void* d_out, int out_size, void* d_ws, size_t ws_size,
                              hipStream_t stream) {
  const float* x   = (const float*)d_in[0];
  const float* Wp  = (const float*)d_in[1];
  const float* bp  = (const float*)d_in[2];
  const float* Wu  = (const float*)d_in[3];
  const float* Wg  = (const float*)d_in[4];
  const float* Wd  = (const float*)d_in[5];
  const float* tb  = (const float*)d_in[6];
  const float* gm  = (const float*)d_in[7];
  const float* wdp = (const float*)d_in[8];
  float* out = (float*)d_out;

  // workspace layout (total ~38 MB)
  char* ws = (char*)d_ws;
  float* scale          = (float*)ws;                                  // 131072 B
  unsigned short* xb    = (unsigned short*)(ws + 131072);              // 8 MB
  unsigned short* wub   = (unsigned short*)(ws + 131072 + 8388608);    // 4 MB
  unsigned short* wgb   = wub + (size_t)DFF * D_DIM;                   // 4 MB
  unsigned short* wdb   = wgb + (size_t)DFF * D_DIM;                   // 4 MB
  unsigned short* hbuf  = wdb + (size_t)DFF * D_DIM;                   // 16 MB

  probe_kernel<<<T_DIM * E_NUM / 4, 256, 0, stream>>>(x, Wp, bp, tb, gm, wdp, scale);
  cvt_kernel<<<T_DIM * D_DIM / 1024, 256, 0, stream>>>(x, xb);

  for (int e = 0; e < E_NUM; e++) {
    const size_t wsz = (size_t)DFF * D_DIM;
    cvt3_kernel<<<3 * (DFF * D_DIM / 1024), 256, 0, stream>>>(
        Wu + e * wsz, Wg + e * wsz, Wd + e * wsz, wub, wgb, wdb);
    dim3 g1(T_DIM / 128, DFF / 128);
    upgate_kernel<<<g1, 256, 0, stream>>>(xb, wub, wgb, scale, e, hbuf);
    dim3 g2(T_DIM / 128, D_DIM / 128);
    down_kernel<<<g2, 256, 0, stream>>>(hbuf, wdb, out, e > 0);
  }
}

// Round 4
// 1102.503 us; speedup vs baseline: 3.2623x; 1.1187x over previous
//
#include <hip/hip_runtime.h>
#include <hip/hip_bf16.h>

#define T_DIM 4096
#define D_DIM 1024
#define DFF   2048
#define E_NUM 8

typedef short short8 __attribute__((ext_vector_type(8)));
typedef float f32x4  __attribute__((ext_vector_type(4)));

__device__ __forceinline__ unsigned short f2bf(float f) {
  union { float f; unsigned u; } v; v.f = f;
  unsigned r = v.u + 0x7FFFu + ((v.u >> 16) & 1u);   // round-to-nearest-even
  return (unsigned short)(r >> 16);
}

__device__ __forceinline__ void load_lds16(const unsigned short* g, unsigned short* l) {
  __builtin_amdgcn_global_load_lds((const __attribute__((address_space(1))) void*)g,
                                   (__attribute__((address_space(3))) void*)l, 16, 0, 0);
}

// ---------------- probe: logits/scale in full fp32 (mask boundary is precision-sensitive)
__global__ void probe_kernel(const float* __restrict__ x, const float* __restrict__ Wp,
                             const float* __restrict__ bp, const float* __restrict__ tb,
                             const float* __restrict__ gm, const float* __restrict__ wdp,
                             float* __restrict__ scale) {
  int wave = threadIdx.x >> 6;
  int lane = threadIdx.x & 63;
  int task = blockIdx.x * 4 + wave;          // one wave per (token, expert)
  int t = task >> 3, e = task & 7;
  const float4* xr = (const float4*)(x + (size_t)t * D_DIM);
  const float4* wr = (const float4*)(Wp + (size_t)e * D_DIM);
  float acc = 0.f;
#pragma unroll
  for (int k = 0; k < 4; k++) {
    float4 a = xr[k * 64 + lane];
    float4 b = wr[k * 64 + lane];
    acc += a.x * b.x + a.y * b.y + a.z * b.z + a.w * b.w;
  }
#pragma unroll
  for (int off = 32; off > 0; off >>= 1) acc += __shfl_down(acc, off);
  if (lane == 0) {
    float logit = acc + bp[e];
    float z = wdp[0] * 0.5f;                                  // w_depth * depth_ratio
    float tau = tb[0] + gm[0] * (z / (1.f + expf(-z)));       // tau_base + gamma*silu(z)
    float s = (logit > tau) ? (1.f / (1.f + expf(-logit))) : 0.f;
    scale[t * E_NUM + e] = s;
  }
}

// ---------------- fp32 -> bf16 converters
__global__ void cvt_kernel(const float* __restrict__ src, unsigned short* __restrict__ dst) {
  int i = blockIdx.x * 256 + threadIdx.x;   // one float4 per thread
  float4 v = ((const float4*)src)[i];
  ushort4 o;
  o.x = f2bf(v.x); o.y = f2bf(v.y); o.z = f2bf(v.z); o.w = f2bf(v.w);
  ((ushort4*)dst)[i] = o;
}

// all-expert weight convert: 3 tensors x 16.78M elements, one dispatch
__global__ void cvt_w_kernel(const float* __restrict__ wu, const float* __restrict__ wg,
                             const float* __restrict__ wdn,
                             unsigned short* __restrict__ ou, unsigned short* __restrict__ og,
                             unsigned short* __restrict__ od) {
  int m = blockIdx.y;
  size_t i = (size_t)blockIdx.x * 256 + threadIdx.x;
  const float* s = (m == 0) ? wu : (m == 1) ? wg : wdn;
  unsigned short* d = (m == 0) ? ou : (m == 1) ? og : od;
  float4 v = ((const float4*)s)[i];
  ushort4 o;
  o.x = f2bf(v.x); o.y = f2bf(v.y); o.z = f2bf(v.z); o.w = f2bf(v.w);
  ((ushort4*)d)[i] = o;
}

// per-expert weight convert (fallback path, 3 x 4.19M elements)
__global__ void cvt3_kernel(const float* __restrict__ wu, const float* __restrict__ wg,
                            const float* __restrict__ wdn,
                            unsigned short* __restrict__ ou, unsigned short* __restrict__ og,
                            unsigned short* __restrict__ od) {
  int b = blockIdx.x;                 // 3 * 2048 blocks; 2048 per matrix
  int m = b >> 11;
  int i = (b & 2047) * 256 + threadIdx.x;
  const float* s = (m == 0) ? wu : (m == 1) ? wg : wdn;
  unsigned short* d = (m == 0) ? ou : (m == 1) ? og : od;
  float4 v = ((const float4*)s)[i];
  ushort4 o;
  o.x = f2bf(v.x); o.y = f2bf(v.y); o.z = f2bf(v.z); o.w = f2bf(v.w);
  ((ushort4*)d)[i] = o;
}

// ---------------- up+gate GEMM, expert = e_base + blockIdx.z
// A: x_bf16 [T][D]; Bu/Bg: bf16 [DFF][D] at base + z*wstride; H at base + z*hstride.
// __launch_bounds__(256,1): prevents accumulator spill (R3: VGPR 64->172 fixed it).
__global__ void __launch_bounds__(256, 1)
upgate_kernel(const unsigned short* __restrict__ A,
              const unsigned short* __restrict__ Bu_base,
              const unsigned short* __restrict__ Bg_base,
              size_t wstride, size_t hstride,
              const float* __restrict__ scale, int e_base,
              unsigned short* __restrict__ H_base) {
  __shared__ unsigned short smem[3 * 128 * 32];          // 24576 B staging
  unsigned short* sA = smem;
  unsigned short* sU = smem + 4096;
  unsigned short* sG = smem + 8192;
  const int e = e_base + blockIdx.z;
  const unsigned short* Bu = Bu_base + (size_t)blockIdx.z * wstride;
  const unsigned short* Bg = Bg_base + (size_t)blockIdx.z * wstride;
  unsigned short* H = H_base + (size_t)blockIdx.z * hstride;
  const int tid = threadIdx.x;
  const int wave = tid >> 6, lane = tid & 63;
  const int quad = lane >> 4, l15 = lane & 15;
  const int wm = (wave >> 1) * 64, wn = (wave & 1) * 64;
  const int rowA0 = blockIdx.x * 128;
  const int rowB0 = blockIdx.y * 128;

  f32x4 accU[4][4], accG[4][4];
#pragma unroll
  for (int i = 0; i < 4; i++)
#pragma unroll
    for (int j = 0; j < 4; j++) {
      accU[i][j] = (f32x4){0.f, 0.f, 0.f, 0.f};
      accG[i][j] = (f32x4){0.f, 0.f, 0.f, 0.f};
    }

  const int j0 = tid, j1 = tid + 256;          // 512 x 16B chunks per 8KB tile
  const int ar0 = rowA0 + (j0 >> 2), ar1 = rowA0 + (j1 >> 2);
  const int br0 = rowB0 + (j0 >> 2), br1 = rowB0 + (j1 >> 2);
  const int c0 = (j0 & 3) * 8, c1 = (j1 & 3) * 8;

  for (int k0 = 0; k0 < D_DIM; k0 += 32) {
    __syncthreads();
    load_lds16(A  + (size_t)ar0 * D_DIM + k0 + c0, sA + j0 * 8);
    load_lds16(A  + (size_t)ar1 * D_DIM + k0 + c1, sA + j1 * 8);
    load_lds16(Bu + (size_t)br0 * D_DIM + k0 + c0, sU + j0 * 8);
    load_lds16(Bu + (size_t)br1 * D_DIM + k0 + c1, sU + j1 * 8);
    load_lds16(Bg + (size_t)br0 * D_DIM + k0 + c0, sG + j0 * 8);
    load_lds16(Bg + (size_t)br1 * D_DIM + k0 + c1, sG + j1 * 8);
    __syncthreads();

    short8 af[4], bu[4], bg[4];
#pragma unroll
    for (int mt = 0; mt < 4; mt++)
      af[mt] = *(const short8*)(sA + (wm + mt * 16 + l15) * 32 + quad * 8);
#pragma unroll
    for (int nt = 0; nt < 4; nt++) {
      bu[nt] = *(const short8*)(sU + (wn + nt * 16 + l15) * 32 + quad * 8);
      bg[nt] = *(const short8*)(sG + (wn + nt * 16 + l15) * 32 + quad * 8);
    }
#pragma unroll
    for (int mt = 0; mt < 4; mt++)
#pragma unroll
      for (int nt = 0; nt < 4; nt++) {
        accU[mt][nt] = __builtin_amdgcn_mfma_f32_16x16x32_bf16(af[mt], bu[nt], accU[mt][nt], 0, 0, 0);
        accG[mt][nt] = __builtin_amdgcn_mfma_f32_16x16x32_bf16(af[mt], bg[nt], accG[mt][nt], 0, 0, 0);
      }
  }

  // epilogue: h' = scale[t,e] * up * silu(gate)  (C/D: col=lane&15, row=quad*4+reg)
#pragma unroll
  for (int mt = 0; mt < 4; mt++) {
#pragma unroll
    for (int r = 0; r < 4; r++) {
      int row = rowA0 + wm + mt * 16 + quad * 4 + r;
      float s = scale[row * E_NUM + e];
#pragma unroll
      for (int nt = 0; nt < 4; nt++) {
        int col = rowB0 + wn + nt * 16 + l15;
        float u = accU[mt][nt][r];
        float g = accG[mt][nt][r];
        float h = s * u * (g / (1.f + __expf(-g)));
        H[(size_t)row * DFF + col] = f2bf(h);
      }
    }
  }
}

// ---------------- down GEMM: out[t,d] += h_e @ Wd_e^T via fp32 atomicAdd
// A (h): base + z*hstride, [T][DFF]; B (wd): base + z*wstride, [D][DFF]; out pre-zeroed.
__global__ void __launch_bounds__(256, 1)
down_kernel(const unsigned short* __restrict__ A_base,
            const unsigned short* __restrict__ B_base,
            size_t hstride, size_t wstride,
            float* __restrict__ out) {
  __shared__ unsigned short smem[2 * 128 * 32];   // 16384 B staging
  unsigned short* sA = smem;
  unsigned short* sB = smem + 4096;
  const unsigned short* A = A_base + (size_t)blockIdx.z * hstride;
  const unsigned short* B = B_base + (size_t)blockIdx.z * wstride;
  const int tid = threadIdx.x;
  const int wave = tid >> 6, lane = tid & 63;
  const int quad = lane >> 4, l15 = lane & 15;
  const int wm = (wave >> 1) * 64, wn = (wave & 1) * 64;
  const int rowA0 = blockIdx.x * 128;
  const int rowB0 = blockIdx.y * 128;

  f32x4 acc[4][4];
#pragma unroll
  for (int i = 0; i < 4; i++)
#pragma unroll
    for (int j = 0; j < 4; j++) acc[i][j] = (f32x4){0.f, 0.f, 0.f, 0.f};

  const int j0 = tid, j1 = tid + 256;
  const int ar0 = rowA0 + (j0 >> 2), ar1 = rowA0 + (j1 >> 2);
  const int br0 = rowB0 + (j0 >> 2), br1 = rowB0 + (j1 >> 2);
  const int c0 = (j0 & 3) * 8, c1 = (j1 & 3) * 8;

  for (int k0 = 0; k0 < DFF; k0 += 32) {
    __syncthreads();
    load_lds16(A + (size_t)ar0 * DFF + k0 + c0, sA + j0 * 8);
    load_lds16(A + (size_t)ar1 * DFF + k0 + c1, sA + j1 * 8);
    load_lds16(B + (size_t)br0 * DFF + k0 + c0, sB + j0 * 8);
    load_lds16(B + (size_t)br1 * DFF + k0 + c1, sB + j1 * 8);
    __syncthreads();

    short8 af[4], bf[4];
#pragma unroll
    for (int mt = 0; mt < 4; mt++)
      af[mt] = *(const short8*)(sA + (wm + mt * 16 + l15) * 32 + quad * 8);
#pragma unroll
    for (int nt = 0; nt < 4; nt++)
      bf[nt] = *(const short8*)(sB + (wn + nt * 16 + l15) * 32 + quad * 8);
#pragma unroll
    for (int mt = 0; mt < 4; mt++)
#pragma unroll
      for (int nt = 0; nt < 4; nt++)
        acc[mt][nt] = __builtin_amdgcn_mfma_f32_16x16x32_bf16(af[mt], bf[nt], acc[mt][nt], 0, 0, 0);
  }

  // expert-combine epilogue: device-scope fp32 atomics (out zeroed by launcher)
#pragma unroll
  for (int mt = 0; mt < 4; mt++) {
#pragma unroll
    for (int r = 0; r < 4; r++) {
      int row = rowA0 + wm + mt * 16 + quad * 4 + r;
#pragma unroll
      for (int nt = 0; nt < 4; nt++) {
        int col = rowB0 + wn + nt * 16 + l15;
        atomicAdd(&out[(size_t)row * D_DIM + col], acc[mt][nt][r]);
      }
    }
  }
}

extern "C" void kernel_launch(void* const* d_in, const int* in_sizes, int n_in,
                              void* d_out, int out_size, void* d_ws, size_t ws_size,
                              hipStream_t stream) {
  const float* x   = (const float*)d_in[0];
  const float* Wp  = (const float*)d_in[1];
  const float* bp  = (const float*)d_in[2];
  const float* Wu  = (const float*)d_in[3];
  const float* Wg  = (const float*)d_in[4];
  const float* Wd  = (const float*)d_in[5];
  const float* tb  = (const float*)d_in[6];
  const float* gm  = (const float*)d_in[7];
  const float* wdp = (const float*)d_in[8];
  float* out = (float*)d_out;

  const size_t WSZ = (size_t)DFF * D_DIM;          // elements per expert weight matrix
  const size_t HSZ = (size_t)T_DIM * DFF;          // elements per expert h

  char* ws = (char*)d_ws;
  float* scale       = (float*)ws;                              // 128 KB
  unsigned short* xb = (unsigned short*)(ws + 131072);          // 8 MB

  probe_kernel<<<T_DIM * E_NUM / 4, 256, 0, stream>>>(x, Wp, bp, tb, gm, wdp, scale);
  cvt_kernel<<<T_DIM * D_DIM / 1024, 256, 0, stream>>>(x, xb);
  hipMemsetAsync(out, 0, (size_t)T_DIM * D_DIM * sizeof(float), stream);

  const size_t FULL_REQ = 131072 + 8388608 + 3 * (WSZ * 2) * E_NUM + HSZ * 2 * E_NUM; // 243.4 MB
  if (ws_size >= FULL_REQ) {
    // -------- fused path: one upgate dispatch (4096 blocks), one down dispatch (2048)
    unsigned short* wub = xb + (size_t)T_DIM * D_DIM;           // 32 MB
    unsigned short* wgb = wub + WSZ * E_NUM;                    // 32 MB
    unsigned short* wdb = wgb + WSZ * E_NUM;                    // 32 MB
    unsigned short* hb  = wdb + WSZ * E_NUM;                    // 128 MB

    dim3 gc(WSZ * E_NUM / 1024, 3);
    cvt_w_kernel<<<gc, 256, 0, stream>>>(Wu, Wg, Wd, wub, wgb, wdb);

    dim3 g1(T_DIM / 128, DFF / 128, E_NUM);
    upgate_kernel<<<g1, 256, 0, stream>>>(xb, wub, wgb, WSZ, HSZ, scale, 0, hb);
    dim3 g2(T_DIM / 128, D_DIM / 128, E_NUM);
    down_kernel<<<g2, 256, 0, stream>>>(hb, wdb, HSZ, WSZ, out);
  } else {
    // -------- fallback (proven R3 structure, ~38 MB): per-expert loop, strides 0
    unsigned short* wub = xb + (size_t)T_DIM * D_DIM;           // 4 MB
    unsigned short* wgb = wub + WSZ;                            // 4 MB
    unsigned short* wdb = wgb + WSZ;                            // 4 MB
    unsigned short* hb  = wdb + WSZ;                            // 16 MB

    for (int e = 0; e < E_NUM; e++) {
      cvt3_kernel<<<3 * (DFF * D_DIM / 1024), 256, 0, stream>>>(
          Wu + e * WSZ, Wg + e * WSZ, Wd + e * WSZ, wub, wgb, wdb);
      dim3 g1(T_DIM / 128, DFF / 128, 1);
      upgate_kernel<<<g1, 256, 0, stream>>>(xb, wub, wgb, 0, 0, scale, e, hb);
      dim3 g2(T_DIM / 128, D_DIM / 128, 1);
      down_kernel<<<g2, 256, 0, stream>>>(hb, wdb, 0, 0, out);
    }
  }
}

// Round 5
// 757.512 us; speedup vs baseline: 4.7481x; 1.4554x over previous
//
#include <hip/hip_runtime.h>
#include <hip/hip_bf16.h>

#define T_DIM 4096
#define D_DIM 1024
#define DFF   2048
#define E_NUM 8

typedef short short8 __attribute__((ext_vector_type(8)));
typedef float f32x4  __attribute__((ext_vector_type(4)));

__device__ __forceinline__ unsigned short f2bf(float f) {
  union { float f; unsigned u; } v; v.f = f;
  unsigned r = v.u + 0x7FFFu + ((v.u >> 16) & 1u);   // round-to-nearest-even
  return (unsigned short)(r >> 16);
}

__device__ __forceinline__ void load_lds16(const unsigned short* g, unsigned short* l) {
  __builtin_amdgcn_global_load_lds((const __attribute__((address_space(1))) void*)g,
                                   (__attribute__((address_space(3))) void*)l, 16, 0, 0);
}

// ---------------- probe: logits/scale in full fp32 (mask boundary is precision-sensitive)
__global__ void probe_kernel(const float* __restrict__ x, const float* __restrict__ Wp,
                             const float* __restrict__ bp, const float* __restrict__ tb,
                             const float* __restrict__ gm, const float* __restrict__ wdp,
                             float* __restrict__ scale) {
  int wave = threadIdx.x >> 6;
  int lane = threadIdx.x & 63;
  int task = blockIdx.x * 4 + wave;          // one wave per (token, expert)
  int t = task >> 3, e = task & 7;
  const float4* xr = (const float4*)(x + (size_t)t * D_DIM);
  const float4* wr = (const float4*)(Wp + (size_t)e * D_DIM);
  float acc = 0.f;
#pragma unroll
  for (int k = 0; k < 4; k++) {
    float4 a = xr[k * 64 + lane];
    float4 b = wr[k * 64 + lane];
    acc += a.x * b.x + a.y * b.y + a.z * b.z + a.w * b.w;
  }
#pragma unroll
  for (int off = 32; off > 0; off >>= 1) acc += __shfl_down(acc, off);
  if (lane == 0) {
    float logit = acc + bp[e];
    float z = wdp[0] * 0.5f;                                  // w_depth * depth_ratio
    float tau = tb[0] + gm[0] * (z / (1.f + expf(-z)));       // tau_base + gamma*silu(z)
    float s = (logit > tau) ? (1.f / (1.f + expf(-logit))) : 0.f;
    scale[t * E_NUM + e] = s;
  }
}

// ---------------- fp32 -> bf16 converters
__global__ void cvt_kernel(const float* __restrict__ src, unsigned short* __restrict__ dst) {
  int i = blockIdx.x * 256 + threadIdx.x;   // one float4 per thread
  float4 v = ((const float4*)src)[i];
  ushort4 o;
  o.x = f2bf(v.x); o.y = f2bf(v.y); o.z = f2bf(v.z); o.w = f2bf(v.w);
  ((ushort4*)dst)[i] = o;
}

// all-expert weight convert: 3 tensors x 16.78M elements, one dispatch
__global__ void cvt_w_kernel(const float* __restrict__ wu, const float* __restrict__ wg,
                             const float* __restrict__ wdn,
                             unsigned short* __restrict__ ou, unsigned short* __restrict__ og,
                             unsigned short* __restrict__ od) {
  int m = blockIdx.y;
  size_t i = (size_t)blockIdx.x * 256 + threadIdx.x;
  const float* s = (m == 0) ? wu : (m == 1) ? wg : wdn;
  unsigned short* d = (m == 0) ? ou : (m == 1) ? og : od;
  float4 v = ((const float4*)s)[i];
  ushort4 o;
  o.x = f2bf(v.x); o.y = f2bf(v.y); o.z = f2bf(v.z); o.w = f2bf(v.w);
  ((ushort4*)d)[i] = o;
}

// per-expert weight convert (fallback path, 3 x 4.19M elements)
__global__ void cvt3_kernel(const float* __restrict__ wu, const float* __restrict__ wg,
                            const float* __restrict__ wdn,
                            unsigned short* __restrict__ ou, unsigned short* __restrict__ og,
                            unsigned short* __restrict__ od) {
  int b = blockIdx.x;                 // 3 * 2048 blocks; 2048 per matrix
  int m = b >> 11;
  int i = (b & 2047) * 256 + threadIdx.x;
  const float* s = (m == 0) ? wu : (m == 1) ? wg : wdn;
  unsigned short* d = (m == 0) ? ou : (m == 1) ? og : od;
  float4 v = ((const float4*)s)[i];
  ushort4 o;
  o.x = f2bf(v.x); o.y = f2bf(v.y); o.z = f2bf(v.z); o.w = f2bf(v.w);
  ((ushort4*)d)[i] = o;
}

// ---------------- up+gate GEMM, expert = e_base + blockIdx.z
// A: x_bf16 [T][D]; Bu/Bg: bf16 [DFF][D] at base + z*wstride; H at base + z*hstride.
// __launch_bounds__(256,2): R4 showed (256,1) -> ~300 regs/wave (172 VGPR + 128
// AGPR acc) -> 1 wave/SIMD -> Occupancy 12%, zero latency hiding across the
// barrier drain. Budget 256 regs fits the ~220 live values -> 2 blocks/CU.
__global__ void __launch_bounds__(256, 2)
upgate_kernel(const unsigned short* __restrict__ A,
              const unsigned short* __restrict__ Bu_base,
              const unsigned short* __restrict__ Bg_base,
              size_t wstride, size_t hstride,
              const float* __restrict__ scale, int e_base,
              unsigned short* __restrict__ H_base) {
  __shared__ unsigned short smem[3 * 128 * 32];          // 24576 B staging
  unsigned short* sA = smem;
  unsigned short* sU = smem + 4096;
  unsigned short* sG = smem + 8192;
  const int e = e_base + blockIdx.z;
  const unsigned short* Bu = Bu_base + (size_t)blockIdx.z * wstride;
  const unsigned short* Bg = Bg_base + (size_t)blockIdx.z * wstride;
  unsigned short* H = H_base + (size_t)blockIdx.z * hstride;
  const int tid = threadIdx.x;
  const int wave = tid >> 6, lane = tid & 63;
  const int quad = lane >> 4, l15 = lane & 15;
  const int wm = (wave >> 1) * 64, wn = (wave & 1) * 64;
  const int rowA0 = blockIdx.x * 128;
  const int rowB0 = blockIdx.y * 128;

  f32x4 accU[4][4], accG[4][4];
#pragma unroll
  for (int i = 0; i < 4; i++)
#pragma unroll
    for (int j = 0; j < 4; j++) {
      accU[i][j] = (f32x4){0.f, 0.f, 0.f, 0.f};
      accG[i][j] = (f32x4){0.f, 0.f, 0.f, 0.f};
    }

  const int j0 = tid, j1 = tid + 256;          // 512 x 16B chunks per 8KB tile
  const int ar0 = rowA0 + (j0 >> 2), ar1 = rowA0 + (j1 >> 2);
  const int br0 = rowB0 + (j0 >> 2), br1 = rowB0 + (j1 >> 2);
  const int c0 = (j0 & 3) * 8, c1 = (j1 & 3) * 8;

  for (int k0 = 0; k0 < D_DIM; k0 += 32) {
    __syncthreads();
    load_lds16(A  + (size_t)ar0 * D_DIM + k0 + c0, sA + j0 * 8);
    load_lds16(A  + (size_t)ar1 * D_DIM + k0 + c1, sA + j1 * 8);
    load_lds16(Bu + (size_t)br0 * D_DIM + k0 + c0, sU + j0 * 8);
    load_lds16(Bu + (size_t)br1 * D_DIM + k0 + c1, sU + j1 * 8);
    load_lds16(Bg + (size_t)br0 * D_DIM + k0 + c0, sG + j0 * 8);
    load_lds16(Bg + (size_t)br1 * D_DIM + k0 + c1, sG + j1 * 8);
    __syncthreads();

    short8 af[4], bu[4], bg[4];
#pragma unroll
    for (int mt = 0; mt < 4; mt++)
      af[mt] = *(const short8*)(sA + (wm + mt * 16 + l15) * 32 + quad * 8);
#pragma unroll
    for (int nt = 0; nt < 4; nt++) {
      bu[nt] = *(const short8*)(sU + (wn + nt * 16 + l15) * 32 + quad * 8);
      bg[nt] = *(const short8*)(sG + (wn + nt * 16 + l15) * 32 + quad * 8);
    }
#pragma unroll
    for (int mt = 0; mt < 4; mt++)
#pragma unroll
      for (int nt = 0; nt < 4; nt++) {
        accU[mt][nt] = __builtin_amdgcn_mfma_f32_16x16x32_bf16(af[mt], bu[nt], accU[mt][nt], 0, 0, 0);
        accG[mt][nt] = __builtin_amdgcn_mfma_f32_16x16x32_bf16(af[mt], bg[nt], accG[mt][nt], 0, 0, 0);
      }
  }

  // epilogue: h' = scale[t,e] * up * silu(gate)  (C/D: col=lane&15, row=quad*4+reg)
#pragma unroll
  for (int mt = 0; mt < 4; mt++) {
#pragma unroll
    for (int r = 0; r < 4; r++) {
      int row = rowA0 + wm + mt * 16 + quad * 4 + r;
      float s = scale[row * E_NUM + e];
#pragma unroll
      for (int nt = 0; nt < 4; nt++) {
        int col = rowB0 + wn + nt * 16 + l15;
        float u = accU[mt][nt][r];
        float g = accG[mt][nt][r];
        float h = s * u * (g / (1.f + __expf(-g)));
        H[(size_t)row * DFF + col] = f2bf(h);
      }
    }
  }
}

// ---------------- down GEMM: out[t,d] += h_e @ Wd_e^T via fp32 atomicAdd
// A (h): base + z*hstride, [T][DFF]; B (wd): base + z*wstride, [D][DFF]; out pre-zeroed.
__global__ void __launch_bounds__(256, 2)
down_kernel(const unsigned short* __restrict__ A_base,
            const unsigned short* __restrict__ B_base,
            size_t hstride, size_t wstride,
            float* __restrict__ out) {
  __shared__ unsigned short smem[2 * 128 * 32];   // 16384 B staging
  unsigned short* sA = smem;
  unsigned short* sB = smem + 4096;
  const unsigned short* A = A_base + (size_t)blockIdx.z * hstride;
  const unsigned short* B = B_base + (size_t)blockIdx.z * wstride;
  const int tid = threadIdx.x;
  const int wave = tid >> 6, lane = tid & 63;
  const int quad = lane >> 4, l15 = lane & 15;
  const int wm = (wave >> 1) * 64, wn = (wave & 1) * 64;
  const int rowA0 = blockIdx.x * 128;
  const int rowB0 = blockIdx.y * 128;

  f32x4 acc[4][4];
#pragma unroll
  for (int i = 0; i < 4; i++)
#pragma unroll
    for (int j = 0; j < 4; j++) acc[i][j] = (f32x4){0.f, 0.f, 0.f, 0.f};

  const int j0 = tid, j1 = tid + 256;
  const int ar0 = rowA0 + (j0 >> 2), ar1 = rowA0 + (j1 >> 2);
  const int br0 = rowB0 + (j0 >> 2), br1 = rowB0 + (j1 >> 2);
  const int c0 = (j0 & 3) * 8, c1 = (j1 & 3) * 8;

  for (int k0 = 0; k0 < DFF; k0 += 32) {
    __syncthreads();
    load_lds16(A + (size_t)ar0 * DFF + k0 + c0, sA + j0 * 8);
    load_lds16(A + (size_t)ar1 * DFF + k0 + c1, sA + j1 * 8);
    load_lds16(B + (size_t)br0 * DFF + k0 + c0, sB + j0 * 8);
    load_lds16(B + (size_t)br1 * DFF + k0 + c1, sB + j1 * 8);
    __syncthreads();

    short8 af[4], bf[4];
#pragma unroll
    for (int mt = 0; mt < 4; mt++)
      af[mt] = *(const short8*)(sA + (wm + mt * 16 + l15) * 32 + quad * 8);
#pragma unroll
    for (int nt = 0; nt < 4; nt++)
      bf[nt] = *(const short8*)(sB + (wn + nt * 16 + l15) * 32 + quad * 8);
#pragma unroll
    for (int mt = 0; mt < 4; mt++)
#pragma unroll
      for (int nt = 0; nt < 4; nt++)
        acc[mt][nt] = __builtin_amdgcn_mfma_f32_16x16x32_bf16(af[mt], bf[nt], acc[mt][nt], 0, 0, 0);
  }

  // expert-combine epilogue: device-scope fp32 atomics (out zeroed by launcher)
#pragma unroll
  for (int mt = 0; mt < 4; mt++) {
#pragma unroll
    for (int r = 0; r < 4; r++) {
      int row = rowA0 + wm + mt * 16 + quad * 4 + r;
#pragma unroll
      for (int nt = 0; nt < 4; nt++) {
        int col = rowB0 + wn + nt * 16 + l15;
        atomicAdd(&out[(size_t)row * D_DIM + col], acc[mt][nt][r]);
      }
    }
  }
}

extern "C" void kernel_launch(void* const* d_in, const int* in_sizes, int n_in,
                              void* d_out, int out_size, void* d_ws, size_t ws_size,
                              hipStream_t stream) {
  const float* x   = (const float*)d_in[0];
  const float* Wp  = (const float*)d_in[1];
  const float* bp  = (const float*)d_in[2];
  const float* Wu  = (const float*)d_in[3];
  const float* Wg  = (const float*)d_in[4];
  const float* Wd  = (const float*)d_in[5];
  const float* tb  = (const float*)d_in[6];
  const float* gm  = (const float*)d_in[7];
  const float* wdp = (const float*)d_in[8];
  float* out = (float*)d_out;

  const size_t WSZ = (size_t)DFF * D_DIM;          // elements per expert weight matrix
  const size_t HSZ = (size_t)T_DIM * DFF;          // elements per expert h

  char* ws = (char*)d_ws;
  float* scale       = (float*)ws;                              // 128 KB
  unsigned short* xb = (unsigned short*)(ws + 131072);          // 8 MB

  probe_kernel<<<T_DIM * E_NUM / 4, 256, 0, stream>>>(x, Wp, bp, tb, gm, wdp, scale);
  cvt_kernel<<<T_DIM * D_DIM / 1024, 256, 0, stream>>>(x, xb);
  hipMemsetAsync(out, 0, (size_t)T_DIM * D_DIM * sizeof(float), stream);

  const size_t FULL_REQ = 131072 + 8388608 + 3 * (WSZ * 2) * E_NUM + HSZ * 2 * E_NUM; // 243.4 MB
  if (ws_size >= FULL_REQ) {
    // -------- fused path: one upgate dispatch (4096 blocks), one down dispatch (2048)
    unsigned short* wub = xb + (size_t)T_DIM * D_DIM;           // 32 MB
    unsigned short* wgb = wub + WSZ * E_NUM;                    // 32 MB
    unsigned short* wdb = wgb + WSZ * E_NUM;                    // 32 MB
    unsigned short* hb  = wdb + WSZ * E_NUM;                    // 128 MB

    dim3 gc(WSZ * E_NUM / 1024, 3);
    cvt_w_kernel<<<gc, 256, 0, stream>>>(Wu, Wg, Wd, wub, wgb, wdb);

    dim3 g1(T_DIM / 128, DFF / 128, E_NUM);
    upgate_kernel<<<g1, 256, 0, stream>>>(xb, wub, wgb, WSZ, HSZ, scale, 0, hb);
    dim3 g2(T_DIM / 128, D_DIM / 128, E_NUM);
    down_kernel<<<g2, 256, 0, stream>>>(hb, wdb, HSZ, WSZ, out);
  } else {
    // -------- fallback (proven R3 structure, ~38 MB): per-expert loop, strides 0
    unsigned short* wub = xb + (size_t)T_DIM * D_DIM;           // 4 MB
    unsigned short* wgb = wub + WSZ;                            // 4 MB
    unsigned short* wdb = wgb + WSZ;                            // 4 MB
    unsigned short* hb  = wdb + WSZ;                            // 16 MB

    for (int e = 0; e < E_NUM; e++) {
      cvt3_kernel<<<3 * (DFF * D_DIM / 1024), 256, 0, stream>>>(
          Wu + e * WSZ, Wg + e * WSZ, Wd + e * WSZ, wub, wgb, wdb);
      dim3 g1(T_DIM / 128, DFF / 128, 1);
      upgate_kernel<<<g1, 256, 0, stream>>>(xb, wub, wgb, 0, 0, scale, e, hb);
      dim3 g2(T_DIM / 128, D_DIM / 128, 1);
      down_kernel<<<g2, 256, 0, stream>>>(hb, wdb, 0, 0, out);
    }
  }
}